// Round 9
// baseline (214.180 us; speedup 1.0000x reference)
//
#include <hip/hip_runtime.h>
#include <math.h>

// Problem constants (fixed by setup_inputs)
#define HD 32
#define BB 256
#define SS 4096
#define BLK 256           // threads per block (4 waves)
#define NWREC 32          // records per row (32 blocks/row, 1 per block)
#define PREC 36           // floats per record: [L, pad3, y[32]]

typedef short bf16x8 __attribute__((ext_vector_type(8)));
typedef float f32x4 __attribute__((ext_vector_type(4)));

__device__ __forceinline__ float tanh_fast(float x) {
  float e = __builtin_amdgcn_exp2f(x * 2.8853900817779268f); // 2*log2(e)
  return 1.0f - 2.0f * __builtin_amdgcn_rcpf(e + 1.0f);
}
__device__ __forceinline__ float exp_fast(float x) {
  return __builtin_amdgcn_exp2f(x * 1.4426950408889634f);    // log2(e)
}
__device__ __forceinline__ short bf16_trunc(float x) {      // truncate to bf16
  return (short)(__float_as_uint(x) >> 16);
}
__device__ __forceinline__ float hi_part(float x) {         // fp32, low16=0
  return __uint_as_float(__float_as_uint(x) & 0xffff0000u);
}

// Phase 0 (tiny): precompute qb[b][h] = bq+bk + fh[b]@Wq once; pre-pack WkT
// hi/lo bf16 fragments to global (L2-resident for p1).
__global__ void __launch_bounds__(256) bahdanau_p0(
    const float* __restrict__ fh, const float* __restrict__ Wq,
    const float* __restrict__ bq, const float* __restrict__ bk,
    const float* __restrict__ Wk, float* __restrict__ qbP,
    short* __restrict__ wkH, short* __restrict__ wkL) {
  const int tid = threadIdx.x;
  if (blockIdx.x == 32) {  // pack Wk transposed + hi/lo split
    float4 w4 = ((const float4*)Wk)[tid];
    const int k = tid >> 3, h0 = (tid & 7) * 4;
    const float v[4] = {w4.x, w4.y, w4.z, w4.w};
#pragma unroll
    for (int i = 0; i < 4; i++) {
      const float hf = hi_part(v[i]);
      wkH[(h0 + i) * HD + k] = bf16_trunc(v[i]);
      wkL[(h0 + i) * HD + k] = bf16_trunc(v[i] - hf);
    }
  } else {
    const int b = blockIdx.x * 8 + (tid >> 5);
    const int h = tid & 31;
    float acc = bq[h] + bk[h];
    const float* fhb = fh + b * HD;
#pragma unroll
    for (int j = 0; j < HD; j++) acc = fmaf(fhb[j], Wq[j * HD + h], acc);
    qbP[b * HD + h] = acc;
  }
}

// Phase 1 (R8 = R7 with the NT builtin type fixed: ext_vector_type f32x4,
// since __builtin_nontemporal_* rejects HIP_vector_type structs).
// R6 structure (proven) + NON-TEMPORAL loads for the zero-reuse lstm
// stream and NT stores for scores. Six structures all pinned p1 at
// ~50-55us = ~2.8 TB/s read throughput; nt relaxes L2 allocation/tracking
// pressure on the read path if that is part of the ceiling.
__global__ void __launch_bounds__(BLK, 5) bahdanau_p1(
    const float* __restrict__ lstm, const float* __restrict__ qbP,
    const short* __restrict__ wkH, const short* __restrict__ wkL,
    const float* __restrict__ Wv, const float* __restrict__ bv,
    float* __restrict__ scores_out, float* __restrict__ partials) {
  __shared__ float sYp[4][HD];
  __shared__ float sRedL[4];
  const int tid = threadIdx.x;
  const int b = blockIdx.x >> 5;        // 32 blocks per row
  const int seg = blockIdx.x & 31;      // 128-position segment
  const int lane = tid & 63, w = tid >> 6;
  const int col = lane & 15, quad = lane >> 4;

  // ---- X loads first (HBM long pole): 4 x dwordx4 nt, no dependent use
  const float* rp =
      lstm + ((size_t)b * SS + seg * 128 + w * 32 + col) * HD + quad * 8;
  const f32x4 xa0 = __builtin_nontemporal_load((const f32x4*)(rp + 0 * 16 * HD));
  const f32x4 xb0 = __builtin_nontemporal_load((const f32x4*)(rp + 0 * 16 * HD) + 1);
  const f32x4 xa1 = __builtin_nontemporal_load((const f32x4*)(rp + 1 * 16 * HD));
  const f32x4 xb1 = __builtin_nontemporal_load((const f32x4*)(rp + 1 * 16 * HD) + 1);

  // ---- aux (L2-hot, reused by all blocks: keep cached)
  const bf16x8 Ah0 = *(const bf16x8*)&wkH[col * HD + quad * 8];
  const bf16x8 Al0 = *(const bf16x8*)&wkL[col * HD + quad * 8];
  const bf16x8 Ah1 = *(const bf16x8*)&wkH[(16 + col) * HD + quad * 8];
  const bf16x8 Al1 = *(const bf16x8*)&wkL[(16 + col) * HD + quad * 8];
  const float4 qbA = ((const float4*)(qbP + b * HD))[quad];
  const float4 qbB = ((const float4*)(qbP + b * HD))[quad + 4];
  const float4 wvA = ((const float4*)Wv)[quad];
  const float4 wvB = ((const float4*)Wv)[quad + 4];
  const float bv0 = bv[0];

  float lAcc = 0.f;
  float yp[8];
#pragma unroll
  for (int j = 0; j < 8; j++) yp[j] = 0.f;

  const size_t srow = (size_t)b * SS + seg * 128 + w * 32;

#define MT_STEP(mt, XA, XB)                                                    \
  {                                                                            \
    const float xs[8] = {XA[0], XA[1], XA[2], XA[3],                           \
                         XB[0], XB[1], XB[2], XB[3]};                          \
    bf16x8 Bh, Bl;                                                             \
    _Pragma("unroll") for (int j = 0; j < 8; j++) {                            \
      const float hf = hi_part(xs[j]);                                         \
      Bh[j] = bf16_trunc(xs[j]);                                               \
      Bl[j] = bf16_trunc(xs[j] - hf);                                          \
    }                                                                          \
    f32x4 c0 = {0.f, 0.f, 0.f, 0.f}, c1 = {0.f, 0.f, 0.f, 0.f};                \
    c0 = __builtin_amdgcn_mfma_f32_16x16x32_bf16(Ah0, Bh, c0, 0, 0, 0);        \
    c1 = __builtin_amdgcn_mfma_f32_16x16x32_bf16(Ah1, Bh, c1, 0, 0, 0);        \
    c0 = __builtin_amdgcn_mfma_f32_16x16x32_bf16(Al0, Bh, c0, 0, 0, 0);        \
    c1 = __builtin_amdgcn_mfma_f32_16x16x32_bf16(Al1, Bh, c1, 0, 0, 0);        \
    c0 = __builtin_amdgcn_mfma_f32_16x16x32_bf16(Ah0, Bl, c0, 0, 0, 0);        \
    c1 = __builtin_amdgcn_mfma_f32_16x16x32_bf16(Ah1, Bl, c1, 0, 0, 0);        \
    float t = tanh_fast(c0[0] + qbA.x) * wvA.x;                                \
    t = fmaf(tanh_fast(c0[1] + qbA.y), wvA.y, t);                              \
    t = fmaf(tanh_fast(c0[2] + qbA.z), wvA.z, t);                              \
    t = fmaf(tanh_fast(c0[3] + qbA.w), wvA.w, t);                              \
    t = fmaf(tanh_fast(c1[0] + qbB.x), wvB.x, t);                              \
    t = fmaf(tanh_fast(c1[1] + qbB.y), wvB.y, t);                              \
    t = fmaf(tanh_fast(c1[2] + qbB.z), wvB.z, t);                              \
    t = fmaf(tanh_fast(c1[3] + qbB.w), wvB.w, t);                              \
    t += __shfl_xor(t, 16, 64);                                                \
    t += __shfl_xor(t, 32, 64);                                                \
    const float e_m = exp_fast(t + bv0); /* e for pos=col, in every lane */    \
    if (lane < 16)                                                             \
      __builtin_nontemporal_store(e_m, scores_out + srow + (mt)*16 + lane);    \
    lAcc += (lane < 16) ? e_m : 0.f;                                           \
    _Pragma("unroll") for (int j = 0; j < 8; j++)                              \
        yp[j] = fmaf(e_m, xs[j], yp[j]);                                       \
  }

  MT_STEP(0, xa0, xb0)
  MT_STEP(1, xa1, xb1)
#undef MT_STEP

  // reduce y over the 16 cols of this quad's h-slice (within-wave)
#pragma unroll
  for (int j = 0; j < 8; j++) {
    yp[j] += __shfl_xor(yp[j], 1, 64);
    yp[j] += __shfl_xor(yp[j], 2, 64);
    yp[j] += __shfl_xor(yp[j], 4, 64);
    yp[j] += __shfl_xor(yp[j], 8, 64);
  }
#pragma unroll
  for (int off = 32; off >= 1; off >>= 1) lAcc += __shfl_xor(lAcc, off, 64);

  if (col == 0) {  // lanes 0,16,32,48 own h = quad*8 .. +8
#pragma unroll
    for (int j = 0; j < 8; j++) sYp[w][quad * 8 + j] = yp[j];
  }
  if (lane == 0) sRedL[w] = lAcc;
  __syncthreads();

  if (tid < HD) {  // one record per block
    float* rec = partials + (size_t)blockIdx.x * PREC;
    rec[4 + tid] = sYp[0][tid] + sYp[1][tid] + sYp[2][tid] + sYp[3][tid];
    if (tid == 0) rec[0] = sRedL[0] + sRedL[1] + sRedL[2] + sRedL[3];
  }
}

// Phase 2: 1024 blocks; block scales 1024 consecutive scores (f32x4/thread)
// of row b = blk>>2. Sub-block 0 also builds ctx = (Y@Wk)/L + bk.
// NT on the streaming score fixup (written once, never re-read by GPU).
__global__ void __launch_bounds__(BLK) bahdanau_p2(
    const float* __restrict__ partials, const float* __restrict__ Wk,
    const float* __restrict__ bk, float* __restrict__ ctx_out,
    float* __restrict__ scores) {
  const int blk = blockIdx.x;
  const int b = blk >> 2;
  const int tid = threadIdx.x;
  __shared__ float sY[HD];

  float L = 0.f;
#pragma unroll 8
  for (int c = 0; c < NWREC; c++)
    L += partials[(size_t)(b * NWREC + c) * PREC];
  const float invL = __builtin_amdgcn_rcpf(L);

  if ((blk & 3) == 0) {   // block-uniform branch: barrier inside is legal
    if (tid < HD) {
      float y = 0.f;
#pragma unroll 8
      for (int c = 0; c < NWREC; c++)
        y += partials[(size_t)(b * NWREC + c) * PREC + 4 + tid];
      sY[tid] = y;
    }
    __syncthreads();
    if (tid < HD) {
      float cv = bk[tid] * L;
#pragma unroll
      for (int j = 0; j < HD; j++) cv = fmaf(sY[j], Wk[j * HD + tid], cv);
      ctx_out[b * HD + tid] = cv * invL;
    }
  }

  f32x4* srow = (f32x4*)(scores + (size_t)b * SS + (blk & 3) * 1024);
  f32x4 s = __builtin_nontemporal_load(srow + tid);
  s[0] *= invL; s[1] *= invL; s[2] *= invL; s[3] *= invL;
  __builtin_nontemporal_store(s, srow + tid);
}

extern "C" void kernel_launch(void* const* d_in, const int* in_sizes, int n_in,
                              void* d_out, int out_size, void* d_ws,
                              size_t ws_size, hipStream_t stream) {
  const float* lstm = (const float*)d_in[0];
  const float* fh   = (const float*)d_in[1];
  const float* Wq   = (const float*)d_in[2];
  const float* bq   = (const float*)d_in[3];
  const float* Wk   = (const float*)d_in[4];
  const float* bk   = (const float*)d_in[5];
  const float* Wv   = (const float*)d_in[6];
  const float* bv   = (const float*)d_in[7];

  float* out = (float*)d_out;
  float* ctx_out = out;           // context: B*H floats
  float* scores = out + BB * HD;  // att_weights region (e then normalized)

  // workspace carve (all 16B-aligned):
  float* partials = (float*)d_ws;                          // 8192*36*4 B
  short* wkH = (short*)((char*)d_ws + (size_t)BB * NWREC * PREC * 4);
  short* wkL = wkH + HD * HD;                              // +2 KB
  float* qbP = (float*)(wkL + HD * HD);                    // +2 KB

  bahdanau_p0<<<33, 256, 0, stream>>>(fh, Wq, bq, bk, Wk, qbP, wkH, wkL);
  bahdanau_p1<<<BB * 32, BLK, 0, stream>>>(lstm, qbP, wkH, wkL, Wv, bv,
                                           scores, partials);
  bahdanau_p2<<<BB * 4, BLK, 0, stream>>>(partials, Wk, bk, ctx_out, scores);
}

// Round 10
// 207.686 us; speedup vs baseline: 1.0313x; 1.0313x over previous
//
#include <hip/hip_runtime.h>
#include <math.h>

// Problem constants (fixed by setup_inputs)
#define HD 32
#define BB 256
#define SS 4096
#define BLK 256           // threads per block (4 waves)
#define NWREC 32          // records per row (32 blocks/row, 1 per block)
#define PREC 36           // floats per record: [L, pad3, y[32]]

typedef short bf16x8 __attribute__((ext_vector_type(8)));
typedef float f32x4 __attribute__((ext_vector_type(4)));

__device__ __forceinline__ float tanh_fast(float x) {
  float e = __builtin_amdgcn_exp2f(x * 2.8853900817779268f); // 2*log2(e)
  return 1.0f - 2.0f * __builtin_amdgcn_rcpf(e + 1.0f);
}
__device__ __forceinline__ float exp_fast(float x) {
  return __builtin_amdgcn_exp2f(x * 1.4426950408889634f);    // log2(e)
}
__device__ __forceinline__ short bf16_trunc(float x) {      // truncate to bf16
  return (short)(__float_as_uint(x) >> 16);
}
__device__ __forceinline__ float hi_part(float x) {         // fp32, low16=0
  return __uint_as_float(__float_as_uint(x) & 0xffff0000u);
}

// Phase 0 (tiny): precompute qb[b][h] = bq+bk + fh[b]@Wq once; pre-pack WkT
// hi/lo bf16 fragments to global (L2-resident for p1).
__global__ void __launch_bounds__(256) bahdanau_p0(
    const float* __restrict__ fh, const float* __restrict__ Wq,
    const float* __restrict__ bq, const float* __restrict__ bk,
    const float* __restrict__ Wk, float* __restrict__ qbP,
    short* __restrict__ wkH, short* __restrict__ wkL) {
  const int tid = threadIdx.x;
  if (blockIdx.x == 32) {  // pack Wk transposed + hi/lo split
    float4 w4 = ((const float4*)Wk)[tid];
    const int k = tid >> 3, h0 = (tid & 7) * 4;
    const float v[4] = {w4.x, w4.y, w4.z, w4.w};
#pragma unroll
    for (int i = 0; i < 4; i++) {
      const float hf = hi_part(v[i]);
      wkH[(h0 + i) * HD + k] = bf16_trunc(v[i]);
      wkL[(h0 + i) * HD + k] = bf16_trunc(v[i] - hf);
    }
  } else {
    const int b = blockIdx.x * 8 + (tid >> 5);
    const int h = tid & 31;
    float acc = bq[h] + bk[h];
    const float* fhb = fh + b * HD;
#pragma unroll
    for (int j = 0; j < HD; j++) acc = fmaf(fhb[j], Wq[j * HD + h], acc);
    qbP[b * HD + h] = acc;
  }
}

// Phase 1 (R10 = exact revert to the best verified kernel, R6 @ 206.09us).
// NT (R9) regressed -8us: lstm (128MB) is L3-resident; nt bypassed L3 and
// raised read latency in a latency-bound regime. 8192 blocks x 4 waves;
// each wave owns 32 positions (2 MT steps, 4 upfront dwordx4). p1 runs at
// ~2.75 TB/s read = ~87% of the chip's demonstrated streaming-read rate
// (m13 copy: 3.15 TB/s/direction); seven structural variants all within
// noise of this operating point.
__global__ void __launch_bounds__(BLK, 5) bahdanau_p1(
    const float* __restrict__ lstm, const float* __restrict__ qbP,
    const short* __restrict__ wkH, const short* __restrict__ wkL,
    const float* __restrict__ Wv, const float* __restrict__ bv,
    float* __restrict__ scores_out, float* __restrict__ partials) {
  __shared__ float sYp[4][HD];
  __shared__ float sRedL[4];
  const int tid = threadIdx.x;
  const int b = blockIdx.x >> 5;        // 32 blocks per row
  const int seg = blockIdx.x & 31;      // 128-position segment
  const int lane = tid & 63, w = tid >> 6;
  const int col = lane & 15, quad = lane >> 4;

  // ---- X loads first (HBM long pole): 4 x dwordx4, no dependent use
  const float* rp =
      lstm + ((size_t)b * SS + seg * 128 + w * 32 + col) * HD + quad * 8;
  const float4 xa0 = ((const float4*)(rp + 0 * 16 * HD))[0];
  const float4 xb0 = ((const float4*)(rp + 0 * 16 * HD))[1];
  const float4 xa1 = ((const float4*)(rp + 1 * 16 * HD))[0];
  const float4 xb1 = ((const float4*)(rp + 1 * 16 * HD))[1];

  // ---- aux (L2-hot after first few blocks)
  const bf16x8 Ah0 = *(const bf16x8*)&wkH[col * HD + quad * 8];
  const bf16x8 Al0 = *(const bf16x8*)&wkL[col * HD + quad * 8];
  const bf16x8 Ah1 = *(const bf16x8*)&wkH[(16 + col) * HD + quad * 8];
  const bf16x8 Al1 = *(const bf16x8*)&wkL[(16 + col) * HD + quad * 8];
  const float4 qbA = ((const float4*)(qbP + b * HD))[quad];
  const float4 qbB = ((const float4*)(qbP + b * HD))[quad + 4];
  const float4 wvA = ((const float4*)Wv)[quad];
  const float4 wvB = ((const float4*)Wv)[quad + 4];
  const float bv0 = bv[0];

  float lAcc = 0.f;
  float yp[8];
#pragma unroll
  for (int j = 0; j < 8; j++) yp[j] = 0.f;

  const size_t srow = (size_t)b * SS + seg * 128 + w * 32;

#define MT_STEP(mt, XA, XB)                                                    \
  {                                                                            \
    const float xs[8] = {XA.x, XA.y, XA.z, XA.w, XB.x, XB.y, XB.z, XB.w};      \
    bf16x8 Bh, Bl;                                                             \
    _Pragma("unroll") for (int j = 0; j < 8; j++) {                            \
      const float hf = hi_part(xs[j]);                                         \
      Bh[j] = bf16_trunc(xs[j]);                                               \
      Bl[j] = bf16_trunc(xs[j] - hf);                                          \
    }                                                                          \
    f32x4 c0 = {0.f, 0.f, 0.f, 0.f}, c1 = {0.f, 0.f, 0.f, 0.f};                \
    c0 = __builtin_amdgcn_mfma_f32_16x16x32_bf16(Ah0, Bh, c0, 0, 0, 0);        \
    c1 = __builtin_amdgcn_mfma_f32_16x16x32_bf16(Ah1, Bh, c1, 0, 0, 0);        \
    c0 = __builtin_amdgcn_mfma_f32_16x16x32_bf16(Al0, Bh, c0, 0, 0, 0);        \
    c1 = __builtin_amdgcn_mfma_f32_16x16x32_bf16(Al1, Bh, c1, 0, 0, 0);        \
    c0 = __builtin_amdgcn_mfma_f32_16x16x32_bf16(Ah0, Bl, c0, 0, 0, 0);        \
    c1 = __builtin_amdgcn_mfma_f32_16x16x32_bf16(Ah1, Bl, c1, 0, 0, 0);        \
    float t = tanh_fast(c0[0] + qbA.x) * wvA.x;                                \
    t = fmaf(tanh_fast(c0[1] + qbA.y), wvA.y, t);                              \
    t = fmaf(tanh_fast(c0[2] + qbA.z), wvA.z, t);                              \
    t = fmaf(tanh_fast(c0[3] + qbA.w), wvA.w, t);                              \
    t = fmaf(tanh_fast(c1[0] + qbB.x), wvB.x, t);                              \
    t = fmaf(tanh_fast(c1[1] + qbB.y), wvB.y, t);                              \
    t = fmaf(tanh_fast(c1[2] + qbB.z), wvB.z, t);                              \
    t = fmaf(tanh_fast(c1[3] + qbB.w), wvB.w, t);                              \
    t += __shfl_xor(t, 16, 64);                                                \
    t += __shfl_xor(t, 32, 64);                                                \
    const float e_m = exp_fast(t + bv0); /* e for pos=col, in every lane */    \
    if (lane < 16) scores_out[srow + (mt)*16 + lane] = e_m;                    \
    lAcc += (lane < 16) ? e_m : 0.f;                                           \
    _Pragma("unroll") for (int j = 0; j < 8; j++)                              \
        yp[j] = fmaf(e_m, xs[j], yp[j]);                                       \
  }

  MT_STEP(0, xa0, xb0)
  MT_STEP(1, xa1, xb1)
#undef MT_STEP

  // reduce y over the 16 cols of this quad's h-slice (within-wave)
#pragma unroll
  for (int j = 0; j < 8; j++) {
    yp[j] += __shfl_xor(yp[j], 1, 64);
    yp[j] += __shfl_xor(yp[j], 2, 64);
    yp[j] += __shfl_xor(yp[j], 4, 64);
    yp[j] += __shfl_xor(yp[j], 8, 64);
  }
#pragma unroll
  for (int off = 32; off >= 1; off >>= 1) lAcc += __shfl_xor(lAcc, off, 64);

  if (col == 0) {  // lanes 0,16,32,48 own h = quad*8 .. +8
#pragma unroll
    for (int j = 0; j < 8; j++) sYp[w][quad * 8 + j] = yp[j];
  }
  if (lane == 0) sRedL[w] = lAcc;
  __syncthreads();

  if (tid < HD) {  // one record per block
    float* rec = partials + (size_t)blockIdx.x * PREC;
    rec[4 + tid] = sYp[0][tid] + sYp[1][tid] + sYp[2][tid] + sYp[3][tid];
    if (tid == 0) rec[0] = sRedL[0] + sRedL[1] + sRedL[2] + sRedL[3];
  }
}

// Phase 2: 1024 blocks; block scales 1024 consecutive scores (float4/thread)
// of row b = blk>>2. Sub-block 0 also builds ctx = (Y@Wk)/L + bk.
__global__ void __launch_bounds__(BLK) bahdanau_p2(
    const float* __restrict__ partials, const float* __restrict__ Wk,
    const float* __restrict__ bk, float* __restrict__ ctx_out,
    float* __restrict__ scores) {
  const int blk = blockIdx.x;
  const int b = blk >> 2;
  const int tid = threadIdx.x;
  __shared__ float sY[HD];

  float L = 0.f;
#pragma unroll 8
  for (int c = 0; c < NWREC; c++)
    L += partials[(size_t)(b * NWREC + c) * PREC];
  const float invL = __builtin_amdgcn_rcpf(L);

  if ((blk & 3) == 0) {   // block-uniform branch: barrier inside is legal
    if (tid < HD) {
      float y = 0.f;
#pragma unroll 8
      for (int c = 0; c < NWREC; c++)
        y += partials[(size_t)(b * NWREC + c) * PREC + 4 + tid];
      sY[tid] = y;
    }
    __syncthreads();
    if (tid < HD) {
      float cv = bk[tid] * L;
#pragma unroll
      for (int j = 0; j < HD; j++) cv = fmaf(sY[j], Wk[j * HD + tid], cv);
      ctx_out[b * HD + tid] = cv * invL;
    }
  }

  float4* srow = (float4*)(scores + (size_t)b * SS + (blk & 3) * 1024);
  float4 s = srow[tid];
  s.x *= invL; s.y *= invL; s.z *= invL; s.w *= invL;
  srow[tid] = s;
}

extern "C" void kernel_launch(void* const* d_in, const int* in_sizes, int n_in,
                              void* d_out, int out_size, void* d_ws,
                              size_t ws_size, hipStream_t stream) {
  const float* lstm = (const float*)d_in[0];
  const float* fh   = (const float*)d_in[1];
  const float* Wq   = (const float*)d_in[2];
  const float* bq   = (const float*)d_in[3];
  const float* Wk   = (const float*)d_in[4];
  const float* bk   = (const float*)d_in[5];
  const float* Wv   = (const float*)d_in[6];
  const float* bv   = (const float*)d_in[7];

  float* out = (float*)d_out;
  float* ctx_out = out;           // context: B*H floats
  float* scores = out + BB * HD;  // att_weights region (e then normalized)

  // workspace carve (all 16B-aligned):
  float* partials = (float*)d_ws;                          // 8192*36*4 B
  short* wkH = (short*)((char*)d_ws + (size_t)BB * NWREC * PREC * 4);
  short* wkL = wkH + HD * HD;                              // +2 KB
  float* qbP = (float*)(wkL + HD * HD);                    // +2 KB

  bahdanau_p0<<<33, 256, 0, stream>>>(fh, Wq, bq, bk, Wk, qbP, wkH, wkL);
  bahdanau_p1<<<BB * 32, BLK, 0, stream>>>(lstm, qbP, wkH, wkL, Wv, bv,
                                           scores, partials);
  bahdanau_p2<<<BB * 4, BLK, 0, stream>>>(partials, Wk, bk, ctx_out, scores);
}